// Round 8
// baseline (302.888 us; speedup 1.0000x reference)
//
#include <hip/hip_runtime.h>

// ChildSumTreeLSTM, complete 8-ary tree, 7 levels, N=299593, MEM=150, IN=300.
// Level d occupies [(8^d-1)/7, (8^(d+1)-1)/7); children of p: 8p+1..8p+8.
// v8: v7 + leaf occupancy push (launch_bounds(320,8), no edge predication on
// leaf), fcsum stored bf16, levels 2/1/0 fused into one single-block kernel.

#define MEMD  150
#define IND   300
#define NINT  37449
#define VOCAB 50000
#define GROW  608          // ushorts per gall row: 152 cols x 4 gates
#define FSTR  152          // hsum/fcsum row stride (elements)

typedef short bf16x8 __attribute__((ext_vector_type(8)));
typedef float f32x16 __attribute__((ext_vector_type(16)));
#define ZERO16 {0,0,0,0,0,0,0,0,0,0,0,0,0,0,0,0}

// ws layout (bytes); high-water 95,584,800 (known-safe from R7)
#define GALL_OFF 0ul           // ushort [VOCAB][152][4]
#define HSB_OFF  60800000ul    // bf16  [NINT][152] h_sum
#define FCS_OFF  72200000ul    // bf16  [NINT][152] sum f*c
#define BPX_OFF  94980000ul    // bf16 B-frags x-side [4][5][19][64][8]
#define BPH_OFF  95380000ul    // bf16 B-frags h-side [4][5][10][64][8]

__device__ __forceinline__ float b2f(unsigned short u) {
    union { unsigned int i; float f; } v; v.i = ((unsigned int)u) << 16; return v.f;
}
__device__ __forceinline__ unsigned short f2b(float f) {
    union { float f; unsigned int i; } v; v.f = f;
    unsigned int x = v.i;
    x += 0x7fffu + ((x >> 16) & 1u);
    return (unsigned short)(x >> 16);
}
__device__ __forceinline__ float sigm(float x) {
    return __builtin_amdgcn_rcpf(1.0f + __expf(-x));
}
__device__ __forceinline__ float tanh_fast(float x) {
    float e = __expf(2.0f * x);
    return 1.0f - 2.0f * __builtin_amdgcn_rcpf(e + 1.0f);
}

// ---- pack weights into 32x32x16 B-fragment order (verified R3-R7) ----
__global__ void pack_w(const float* __restrict__ Wix, const float* __restrict__ Wox,
                       const float* __restrict__ Wux, const float* __restrict__ Wfx,
                       const float* __restrict__ Wih, const float* __restrict__ Woh,
                       const float* __restrict__ Wuh, const float* __restrict__ Wfh,
                       unsigned short* __restrict__ bpx, unsigned short* __restrict__ bph)
{
    const int total_x = 4 * 5 * 19 * 512;
    const int total_h = 4 * 5 * 10 * 512;
    for (int i = blockIdx.x * blockDim.x + threadIdx.x; i < total_x + total_h;
         i += gridDim.x * blockDim.x) {
        if (i < total_x) {
            int e = i & 7, lane = (i >> 3) & 63, rest = i >> 9;
            int ks = rest % 19; rest /= 19;
            int nt = rest % 5;  int g = rest / 5;
            int col = nt * 32 + (lane & 31);
            int k = ks * 16 + ((lane >> 5) << 3) + e;
            const float* W = (g == 0) ? Wix : (g == 1) ? Wox : (g == 2) ? Wux : Wfx;
            bpx[i] = f2b((col < MEMD && k < IND) ? W[col * IND + k] : 0.f);
        } else {
            int j = i - total_x;
            int e = j & 7, lane = (j >> 3) & 63, rest = j >> 9;
            int ks = rest % 10; rest /= 10;
            int nt = rest % 5;  int g = rest / 5;
            int col = nt * 32 + (lane & 31);
            int k = ks * 16 + ((lane >> 5) << 3) + e;
            const float* W = (g == 0) ? Wih : (g == 1) ? Woh : (g == 2) ? Wuh : Wfh;
            bph[j] = f2b((col < MEMD && k < MEMD) ? W[col * MEMD + k] : 0.f);
        }
    }
}

// ---- per-vocab gate projections: gall[v][col][g], biases folded ----
__global__ __launch_bounds__(640, 2)
void vocab_gemm(const float* __restrict__ emb,
                const float* __restrict__ bix, const float* __restrict__ bih,
                const float* __restrict__ box_, const float* __restrict__ boh,
                const float* __restrict__ bux, const float* __restrict__ buh,
                const float* __restrict__ bfx, const float* __restrict__ bfh,
                const unsigned short* __restrict__ bpx_u,
                unsigned short* __restrict__ gall)
{
    __shared__ __align__(16) char sm0[40960];
    const int tid = threadIdx.x, lane = tid & 63, w = tid >> 6;
    const int hi = lane >> 5, ln31 = lane & 31;
    const int tile0 = blockIdx.x * 64;
    const int rowsValid = min(64, VOCAB - tile0);
    const int mt = (w >= 5) ? 1 : 0, nt = w - mt * 5;

    for (int i = tid; i < 64 * 40; i += 640) {
        int r = i / 40, q = i % 40;
        int rr = (r < rowsValid) ? r : 0;
        const float* er = emb + (long)(tile0 + rr) * IND;
        float4 v0 = {0.f,0.f,0.f,0.f}, v1 = {0.f,0.f,0.f,0.f};
        if (q < 38) v0 = *(const float4*)(er + q * 8);
        if (q < 37) v1 = *(const float4*)(er + q * 8 + 4);
        bf16x8 p;
        p[0]=(short)f2b(v0.x); p[1]=(short)f2b(v0.y); p[2]=(short)f2b(v0.z); p[3]=(short)f2b(v0.w);
        p[4]=(short)f2b(v1.x); p[5]=(short)f2b(v1.y); p[6]=(short)f2b(v1.z); p[7]=(short)f2b(v1.w);
        *(bf16x8*)(sm0 + r * 640 + ((q * 16) ^ ((r & 7) << 4))) = p;
    }
    __syncthreads();

    const bf16x8* BX = (const bf16x8*)bpx_u;
    const int row = mt * 32 + ln31;
    const int col = nt * 32 + ln31;
    const bool colv = col < MEMD;
    const int cc = colv ? col : 0;
    const float* b1[4] = {bix, box_, bux, bfx};
    const float* b2[4] = {bih, boh, buh, bfh};

    for (int g = 0; g < 4; ++g) {
        f32x16 acc = ZERO16;
        bf16x8 aC = *(const bf16x8*)(sm0 + row * 640 + ((hi * 16) ^ ((row & 7) << 4)));
        bf16x8 bC = BX[((g * 5 + nt) * 19 + 0) * 64 + lane];
        #pragma unroll
        for (int ks = 0; ks < 19; ++ks) {
            bf16x8 aN, bN;
            if (ks < 18) {
                aN = *(const bf16x8*)(sm0 + row * 640 + (((ks + 1) * 32 + hi * 16) ^ ((row & 7) << 4)));
                bN = BX[((g * 5 + nt) * 19 + ks + 1) * 64 + lane];
            }
            acc = __builtin_amdgcn_mfma_f32_32x32x16_bf16(aC, bC, acc, 0, 0, 0);
            aC = aN; bC = bN;
        }
        float bias = colv ? (b1[g][cc] + b2[g][cc]) : 0.f;
        #pragma unroll
        for (int r = 0; r < 16; ++r) {
            int rloc = mt * 32 + (r & 3) + 8 * (r >> 2) + 4 * hi;
            if (rloc < rowsValid && colv)
                gall[(long)(tile0 + rloc) * GROW + col * 4 + g] = f2b(acc[r] + bias);
        }
    }
}

// ---- per-level kernel: x side gathered from gall; h side MFMA ----
// Leaf (INTERNAL=false): full tiles guaranteed, occupancy-maxed.
template<bool INTERNAL>
__global__ __launch_bounds__(320, INTERNAL ? 2 : 8)
void level_k(const int* __restrict__ tokens,
             const unsigned short* __restrict__ gall,
             const unsigned short* __restrict__ bph_u,
             unsigned short* __restrict__ hsumb, unsigned short* __restrict__ fcsum,
             float* __restrict__ c_out, int base, int cnt, int writePar)
{
    __shared__ __align__(16) char sm0[INTERNAL ? 24576 : 12288];
    __shared__ int toksL[32];
    __shared__ int ptokL[4];
    const int tid = threadIdx.x, lane = tid & 63, w = tid >> 6;
    const int hi = lane >> 5, ln31 = lane & 31;
    const int tile0 = blockIdx.x * 32;
    const int nodeBase = base + tile0;
    const int rowsValid = INTERNAL ? min(32, cnt - tile0) : 32;
    const int p0 = (nodeBase - 1) >> 3;
    const int nt = w;

    if (tid < 32) toksL[tid] = tokens[nodeBase + ((tid < rowsValid) ? tid : 0)];
    if (writePar && tid < 4) ptokL[tid] = tokens[p0 + tid];
    if (INTERNAL) {
        for (int i = tid; i < 32 * 20; i += 320) {
            int r = i / 20, q = i % 20;
            int rr = (r < rowsValid) ? r : 0;
            bf16x8 v = {0,0,0,0,0,0,0,0};
            if (q < 19)
                v = *(const bf16x8*)(hsumb + (long)(nodeBase + rr) * FSTR + q * 8);
            *(bf16x8*)(sm0 + 12288 + r * 384 + ((q * 16) ^ ((r & 7) << 4))) = v;
        }
    }
    __syncthreads();

    const bf16x8* BH = (const bf16x8*)bph_u;
    const int row = ln31;
    const int col = nt * 32 + ln31;
    const bool colv = col < MEMD;
    const int cc = colv ? col : 0;

    f32x16 ai = ZERO16, ao = ZERO16, au = ZERO16;
    if (INTERNAL) {
        const char* hb = sm0 + 12288;
        bf16x8 aC = *(const bf16x8*)(hb + row * 384 + ((hi * 16) ^ ((row & 7) << 4)));
        bf16x8 b0C = BH[((0 * 5 + nt) * 10 + 0) * 64 + lane];
        bf16x8 b1C = BH[((1 * 5 + nt) * 10 + 0) * 64 + lane];
        bf16x8 b2C = BH[((2 * 5 + nt) * 10 + 0) * 64 + lane];
        #pragma unroll
        for (int ks = 0; ks < 10; ++ks) {
            bf16x8 aN, b0N, b1N, b2N;
            if (ks < 9) {
                aN  = *(const bf16x8*)(hb + row * 384 + (((ks + 1) * 32 + hi * 16) ^ ((row & 7) << 4)));
                b0N = BH[((0 * 5 + nt) * 10 + ks + 1) * 64 + lane];
                b1N = BH[((1 * 5 + nt) * 10 + ks + 1) * 64 + lane];
                b2N = BH[((2 * 5 + nt) * 10 + ks + 1) * 64 + lane];
            }
            ai = __builtin_amdgcn_mfma_f32_32x32x16_bf16(aC, b0C, ai, 0, 0, 0);
            ao = __builtin_amdgcn_mfma_f32_32x32x16_bf16(aC, b1C, ao, 0, 0, 0);
            au = __builtin_amdgcn_mfma_f32_32x32x16_bf16(aC, b2C, au, 0, 0, 0);
            aC = aN; b0C = b0N; b1C = b1N; b2C = b2N;
        }
    }

    float cvv[16];
    {
        float hp[4] = {0.f, 0.f, 0.f, 0.f};
        #pragma unroll
        for (int r = 0; r < 16; ++r) {
            int rloc = (r & 3) + 8 * (r >> 2) + 4 * hi;
            bool rv = INTERNAL ? (rloc < rowsValid) : true;
            ushort4 gv = *(const ushort4*)(gall + (long)toksL[rloc] * GROW + cc * 4);
            float fc = 0.f;
            if (INTERNAL) fc = (rv && colv) ? b2f(fcsum[(long)(nodeBase + rloc) * FSTR + col]) : 0.f;
            float iv = sigm((INTERNAL ? ai[r] : 0.f) + b2f(gv.x));
            float ov = sigm((INTERNAL ? ao[r] : 0.f) + b2f(gv.y));
            float uv = tanh_fast((INTERNAL ? au[r] : 0.f) + b2f(gv.z));
            float cv = iv * uv + fc;
            float h = (rv && colv) ? ov * tanh_fast(cv) : 0.f;
            cvv[r] = (rv && colv) ? cv : 0.f;
            if (rv && colv) c_out[(long)(nodeBase + rloc) * MEMD + col] = cv;
            *(unsigned short*)(sm0 + rloc * 384 + ((col * 2) ^ ((rloc & 7) << 4))) = f2b(h);
            hp[r >> 2] += h;
        }
        if (writePar) {
            #pragma unroll
            for (int o = 0; o < 4; ++o) {
                float s = hp[o] + __shfl_xor(hp[o], 32);
                if (lane < 32 && colv && (INTERNAL ? (o * 8 < rowsValid) : true))
                    hsumb[(long)(p0 + o) * FSTR + col] = f2b(s);
            }
        }
    }
    __syncthreads();

    if (writePar) {
        f32x16 ff = ZERO16;
        {
            bf16x8 aC = *(const bf16x8*)(sm0 + row * 384 + ((hi * 16) ^ ((row & 7) << 4)));
            bf16x8 bC = BH[((15 + nt) * 10 + 0) * 64 + lane];
            #pragma unroll
            for (int ks = 0; ks < 10; ++ks) {
                bf16x8 aN, bN;
                if (ks < 9) {
                    aN = *(const bf16x8*)(sm0 + row * 384 + (((ks + 1) * 32 + hi * 16) ^ ((row & 7) << 4)));
                    bN = BH[((15 + nt) * 10 + ks + 1) * 64 + lane];
                }
                ff = __builtin_amdgcn_mfma_f32_32x32x16_bf16(aC, bC, ff, 0, 0, 0);
                aC = aN; bC = bN;
            }
        }
        #pragma unroll
        for (int o = 0; o < 4; ++o) {
            float fx = b2f(gall[(long)ptokL[o] * GROW + cc * 4 + 3]);
            float fp = 0.f;
            #pragma unroll
            for (int q = 0; q < 4; ++q) {
                int r = o * 4 + q;
                fp += sigm(ff[r] + fx) * cvv[r];
            }
            float s = fp + __shfl_xor(fp, 32);
            if (lane < 32 && colv && (INTERNAL ? (o * 8 < rowsValid) : true))
                fcsum[(long)(p0 + o) * FSTR + col] = f2b(s);
        }
    }
}

// ---- fused tail: levels 2 (64 nodes), 1 (8), 0 (1) in one block ----
__global__ __launch_bounds__(320, 2)
void tail_k(const int* __restrict__ tokens,
            const unsigned short* __restrict__ gall,
            const unsigned short* __restrict__ bph_u,
            unsigned short* __restrict__ hsumb, unsigned short* __restrict__ fcsum,
            float* __restrict__ c_out)
{
    __shared__ __align__(16) char sm0[24576];
    __shared__ int toksL[32];
    __shared__ int ptokL[4];
    const int tid = threadIdx.x, lane = tid & 63, w = tid >> 6;
    const int hi = lane >> 5, ln31 = lane & 31;
    const int nt = w;
    const bf16x8* BH = (const bf16x8*)bph_u;
    const int row = ln31;
    const int col = nt * 32 + ln31;
    const bool colv = col < MEMD;
    const int cc = colv ? col : 0;

    const int basesL[3] = {9, 1, 0};
    const int cntsL[3]  = {64, 8, 1};
    const int wpL[3]    = {1, 1, 0};

    for (int li = 0; li < 3; ++li) {
        for (int t0 = 0; t0 < cntsL[li]; t0 += 32) {
            const int nodeBase = basesL[li] + t0;
            const int rowsValid = min(32, cntsL[li] - t0);
            const int p0 = (nodeBase - 1) >> 3;
            const int writePar = wpL[li];

            if (tid < 32) toksL[tid] = tokens[nodeBase + ((tid < rowsValid) ? tid : 0)];
            if (writePar && tid < 4) ptokL[tid] = tokens[p0 + tid];
            for (int i = tid; i < 32 * 20; i += 320) {
                int r = i / 20, q = i % 20;
                int rr = (r < rowsValid) ? r : 0;
                bf16x8 v = {0,0,0,0,0,0,0,0};
                if (q < 19)
                    v = *(const bf16x8*)(hsumb + (long)(nodeBase + rr) * FSTR + q * 8);
                *(bf16x8*)(sm0 + 12288 + r * 384 + ((q * 16) ^ ((r & 7) << 4))) = v;
            }
            __syncthreads();

            f32x16 ai = ZERO16, ao = ZERO16, au = ZERO16;
            {
                const char* hb = sm0 + 12288;
                #pragma unroll
                for (int ks = 0; ks < 10; ++ks) {
                    bf16x8 a = *(const bf16x8*)(hb + row * 384 + ((ks * 32 + hi * 16) ^ ((row & 7) << 4)));
                    ai = __builtin_amdgcn_mfma_f32_32x32x16_bf16(a, BH[((0 * 5 + nt) * 10 + ks) * 64 + lane], ai, 0, 0, 0);
                    ao = __builtin_amdgcn_mfma_f32_32x32x16_bf16(a, BH[((1 * 5 + nt) * 10 + ks) * 64 + lane], ao, 0, 0, 0);
                    au = __builtin_amdgcn_mfma_f32_32x32x16_bf16(a, BH[((2 * 5 + nt) * 10 + ks) * 64 + lane], au, 0, 0, 0);
                }
            }

            float cvv[16];
            {
                float hp[4] = {0.f, 0.f, 0.f, 0.f};
                #pragma unroll
                for (int r = 0; r < 16; ++r) {
                    int rloc = (r & 3) + 8 * (r >> 2) + 4 * hi;
                    bool rv = rloc < rowsValid;
                    ushort4 gv = *(const ushort4*)(gall + (long)toksL[rloc] * GROW + cc * 4);
                    float fc = (rv && colv) ? b2f(fcsum[(long)(nodeBase + rloc) * FSTR + col]) : 0.f;
                    float iv = sigm(ai[r] + b2f(gv.x));
                    float ov = sigm(ao[r] + b2f(gv.y));
                    float uv = tanh_fast(au[r] + b2f(gv.z));
                    float cv = iv * uv + fc;
                    float h = (rv && colv) ? ov * tanh_fast(cv) : 0.f;
                    cvv[r] = (rv && colv) ? cv : 0.f;
                    if (rv && colv) c_out[(long)(nodeBase + rloc) * MEMD + col] = cv;
                    *(unsigned short*)(sm0 + rloc * 384 + ((col * 2) ^ ((rloc & 7) << 4))) = f2b(h);
                    hp[r >> 2] += h;
                }
                if (writePar) {
                    #pragma unroll
                    for (int o = 0; o < 4; ++o) {
                        float s = hp[o] + __shfl_xor(hp[o], 32);
                        if (lane < 32 && colv && o * 8 < rowsValid)
                            hsumb[(long)(p0 + o) * FSTR + col] = f2b(s);
                    }
                }
            }
            __syncthreads();

            if (writePar) {
                f32x16 ff = ZERO16;
                #pragma unroll
                for (int ks = 0; ks < 10; ++ks) {
                    bf16x8 a = *(const bf16x8*)(sm0 + row * 384 + ((ks * 32 + hi * 16) ^ ((row & 7) << 4)));
                    ff = __builtin_amdgcn_mfma_f32_32x32x16_bf16(a, BH[((15 + nt) * 10 + ks) * 64 + lane], ff, 0, 0, 0);
                }
                #pragma unroll
                for (int o = 0; o < 4; ++o) {
                    float fx = b2f(gall[(long)ptokL[o] * GROW + cc * 4 + 3]);
                    float fp = 0.f;
                    #pragma unroll
                    for (int q = 0; q < 4; ++q)
                        fp += sigm(ff[o * 4 + q] + fx) * cvv[o * 4 + q];
                    float s = fp + __shfl_xor(fp, 32);
                    if (lane < 32 && colv && o * 8 < rowsValid)
                        fcsum[(long)(p0 + o) * FSTR + col] = f2b(s);
                }
            }
            __syncthreads();
        }
    }
}

extern "C" void kernel_launch(void* const* d_in, const int* in_sizes, int n_in,
                              void* d_out, int out_size, void* d_ws, size_t ws_size,
                              hipStream_t stream) {
    const int*   tokens = (const int*)d_in[0];
    const float* emb = (const float*)d_in[4];
    const float* Wix = (const float*)d_in[5];  const float* bix = (const float*)d_in[6];
    const float* Wih = (const float*)d_in[7];  const float* bih = (const float*)d_in[8];
    const float* Wfx = (const float*)d_in[9];  const float* bfx = (const float*)d_in[10];
    const float* Wfh = (const float*)d_in[11]; const float* bfh = (const float*)d_in[12];
    const float* Wox = (const float*)d_in[13]; const float* box_ = (const float*)d_in[14];
    const float* Woh = (const float*)d_in[15]; const float* boh = (const float*)d_in[16];
    const float* Wux = (const float*)d_in[17]; const float* bux = (const float*)d_in[18];
    const float* Wuh = (const float*)d_in[19]; const float* buh = (const float*)d_in[20];
    float* c_out = (float*)d_out;
    char* ws = (char*)d_ws;

    unsigned short* gall  = (unsigned short*)(ws + GALL_OFF);
    unsigned short* hsumb = (unsigned short*)(ws + HSB_OFF);
    unsigned short* fcs   = (unsigned short*)(ws + FCS_OFF);
    unsigned short* bpx   = (unsigned short*)(ws + BPX_OFF);
    unsigned short* bph   = (unsigned short*)(ws + BPH_OFF);

    pack_w<<<128, 512, 0, stream>>>(Wix, Wox, Wux, Wfx, Wih, Woh, Wuh, Wfh, bpx, bph);
    vocab_gemm<<<(VOCAB + 63) / 64, 640, 0, stream>>>(
        emb, bix, bih, box_, boh, bux, buh, bfx, bfh, bpx, gall);

    static const int bases[7] = {0, 1, 9, 73, 585, 4681, 37449};
    static const int cnts[7]  = {1, 8, 64, 512, 4096, 32768, 262144};

    level_k<false><<<cnts[6] / 32, 320, 0, stream>>>(
        tokens, gall, bph, hsumb, fcs, c_out, bases[6], cnts[6], 1);
    for (int d = 5; d >= 3; --d) {
        int grid = (cnts[d] + 31) / 32;
        level_k<true><<<grid, 320, 0, stream>>>(
            tokens, gall, bph, hsumb, fcs, c_out, bases[d], cnts[d], 1);
    }
    tail_k<<<1, 320, 0, stream>>>(tokens, gall, bph, hsumb, fcs, c_out);
}